// Round 9
// baseline (154.663 us; speedup 1.0000x reference)
//
#include <hip/hip_runtime.h>

#define NUM_BINS 256
#define HW4 65536                  // float4 per plane (512*512/4)
#define NGROUPS 6                  // {img1,img2} x {c0,c1,c2}
#define BPG 426                    // blocks per group (grid = 426 x 6)
#define CHUNKS 8192                // wave-chunks per group (128 f4 each)
#define THREADS 64                 // one wave per block
#define MAXIT 20                   // ceil(8192/426)

// ---------------------------------------------------------------------------
// Kernel 1: per-lane private u8 sub-histograms, pair-interleaved layout:
//   addr(bin,lane) = (bin>>1)*128 + lane*2 + (bin&1)
// -> bank = lane>>1: 32 banks, 2 lanes/bank for EVERY access (free), any bin.
// Table = 16384 B exactly -> 10 blocks/CU. Batch-8 independent reads +
// in-register dedup; 2-deep prefetch hides HBM latency.
// ---------------------------------------------------------------------------
__global__ __launch_bounds__(THREADS) void hist_kernel(
    const float* __restrict__ img1,
    const float* __restrict__ img2,
    unsigned int* __restrict__ ghist /* [6][256] */) {

    __shared__ unsigned char h8[16384];

    const int lane = threadIdx.x;
    const int lane2 = lane << 1;

    // zero 16384 B: 1024 uint4 / 64 lanes = 16 per lane
    uint4* z = (uint4*)h8;
    #pragma unroll
    for (int i = 0; i < 16; ++i)
        z[i * THREADS + lane] = make_uint4(0u, 0u, 0u, 0u);
    __syncthreads();

    const int blk = blockIdx.x;                // 0..425
    const int group = blockIdx.y;              // 0..5
    const int im = (group >= 3) ? 1 : 0;
    const int c = group - im * 3;
    const float4* __restrict__ base = (const float4*)(im ? img2 : img1);

    // chunk k = blk + it*BPG covers 0..CHUNKS-1 bijectively; wave-uniform it
    const int iters = (blk + (MAXIT - 1) * BPG < CHUNKS) ? MAXIT : (MAXIT - 1);

    // chunk -> address: plane b = k>>9, in-plane f4 j = (k&511)*128
#define SRC(k) (base + ((size_t)(((k) >> 9) * 3 + c) << 16) + (((k)&511) << 7) + lane)

    // 2-deep software pipeline
    float4 va0, vb0, va1, vb1;
    { const float4* s = SRC(blk); va0 = s[0]; vb0 = s[THREADS]; }
    if (iters > 1) { const float4* s = SRC(blk + BPG); va1 = s[0]; vb1 = s[THREADS]; }

    for (int it = 0; it < iters; ++it) {
        float4 na, nb;
        if (it + 2 < iters) {
            const float4* s = SRC(blk + (it + 2) * BPG);
            na = s[0]; nb = s[THREADS];
        }

        const float xs[8] = {va0.x, va0.y, va0.z, va0.w,
                             vb0.x, vb0.y, vb0.z, vb0.w};
        int row[8];
        unsigned v0[8];
        #pragma unroll
        for (int e = 0; e < 8; ++e) {
            const float x = xs[e];
            int bi = (int)(x * 256.0f);            // trunc == floor (x >= 0)
            bi = bi < 0 ? 0 : (bi > 255 ? 255 : bi);
            row[e] = bi;
            // torch.histc: count only x in [0,1]; x==1 -> last bin
            v0[e] = (x >= 0.0f && x <= 1.0f) ? 1u : 0u;
        }

        // in-register dedup: first occurrence absorbs duplicates' counts
        unsigned inc[8], dead[8];
        #pragma unroll
        for (int e = 0; e < 8; ++e) { inc[e] = v0[e]; dead[e] = 0u; }
        #pragma unroll
        for (int i = 0; i < 8; ++i)
            #pragma unroll
            for (int j = i + 1; j < 8; ++j) {
                const unsigned m = (row[i] == row[j]) ? 1u : 0u;
                inc[i] += m & v0[j];
                dead[j] |= m;
            }

        // pair-interleaved addresses; 8 independent reads then guarded writes
        int a[8];
        #pragma unroll
        for (int e = 0; e < 8; ++e)
            a[e] = (((row[e] >> 1) << 7) | lane2) | (row[e] & 1);
        unsigned v[8];
        #pragma unroll
        for (int e = 0; e < 8; ++e)
            v[e] = h8[a[e]];
        #pragma unroll
        for (int e = 0; e < 8; ++e)
            if (!dead[e])
                h8[a[e]] = (unsigned char)(v[e] + inc[e]);

        va0 = va1; vb0 = vb1; va1 = na; vb1 = nb;
    }
#undef SRC
    __syncthreads();

    // flush: stripe s (=128B) holds bins {2s, 2s+1}; lane handles stripes
    // lane and 64+lane. Rotated word reads -> 2 lanes/bank.
    const unsigned* h32 = (const unsigned*)h8;
    #pragma unroll
    for (int pass = 0; pass < 2; ++pass) {
        const int stripe = (pass << 6) | lane;     // 0..127
        const int wbase = stripe << 5;             // 32 words per stripe
        unsigned s0 = 0, s1 = 0;
        #pragma unroll
        for (int w = 0; w < 32; ++w) {
            const unsigned x = h32[wbase + ((w + lane) & 31)];
            s0 += (x & 0xffu) + ((x >> 16) & 0xffu);        // even bin
            s1 += ((x >> 8) & 0xffu) + (x >> 24);           // odd bin
        }
        if (s0) atomicAdd(&ghist[group * NUM_BINS + (stripe << 1)], s0);
        if (s1) atomicAdd(&ghist[group * NUM_BINS + (stripe << 1) + 1], s1);
    }
}

// ---------------------------------------------------------------------------
// Kernel 2: normalize, cumsum, sum |cdf1 - cdf2|, /3. One block, 256 threads.
// ---------------------------------------------------------------------------
__global__ __launch_bounds__(NUM_BINS) void finalize_kernel(
    const unsigned int* __restrict__ hist, float* __restrict__ out) {

    __shared__ float b1[NUM_BINS];
    __shared__ float b2[NUM_BINS];
    __shared__ float red[NUM_BINS / 64];

    const int t = threadIdx.x;
    float acc = 0.0f;

    for (int c = 0; c < 3; ++c) {
        b1[t] = (float)hist[c * NUM_BINS + t];
        b2[t] = (float)hist[(3 + c) * NUM_BINS + t];
        __syncthreads();
        // Hillis-Steele inclusive scan, 8 steps
        for (int off = 1; off < NUM_BINS; off <<= 1) {
            float a1 = 0.0f, a2 = 0.0f;
            if (t >= off) { a1 = b1[t - off]; a2 = b2[t - off]; }
            __syncthreads();
            b1[t] += a1;
            b2[t] += a2;
            __syncthreads();
        }
        acc += fabsf(b1[t] / b1[NUM_BINS - 1] - b2[t] / b2[NUM_BINS - 1]);
        __syncthreads();                  // protect b1/b2 reuse next channel
    }

    #pragma unroll
    for (int off = 32; off > 0; off >>= 1)
        acc += __shfl_down(acc, off, 64);
    if ((t & 63) == 0) red[t >> 6] = acc;
    __syncthreads();
    if (t == 0)
        out[0] = (red[0] + red[1] + red[2] + red[3]) * (1.0f / 3.0f);
}

// ---------------------------------------------------------------------------
extern "C" void kernel_launch(void* const* d_in, const int* in_sizes, int n_in,
                              void* d_out, int out_size, void* d_ws,
                              size_t ws_size, hipStream_t stream) {
    const float* img1 = (const float*)d_in[0];
    const float* img2 = (const float*)d_in[1];
    float* out = (float*)d_out;
    unsigned int* hist = (unsigned int*)d_ws;   // [6][256] uint32

    // d_ws is poisoned to 0xAA before every launch -> zero hist every call
    hipMemsetAsync(hist, 0, NGROUPS * NUM_BINS * sizeof(unsigned int), stream);

    dim3 grid(BPG, NGROUPS);
    hist_kernel<<<grid, THREADS, 0, stream>>>(img1, img2, hist);
    finalize_kernel<<<1, NUM_BINS, 0, stream>>>(hist, out);
}